// Round 6
// baseline (93.624 us; speedup 1.0000x reference)
//
#include <hip/hip_runtime.h>

// LightConv: B=8, T=1024, H=8, S=64, K=31, C=512 (all fp32)
// out[b,t,h*S+s] = sum_k softmax_k(filters[b,t,h,:])[k] * x[b, t+k-15, h*S+s] + bias[h*S+s]
//
// R6: throughput version. v_pk_fma_f32 via ext-vector math; 12-slot rolling
// LDS->register window (VGPR ~100) + __launch_bounds__(256,4) -> 4 blocks/CU
// (16 waves/CU) for cross-wave VALU/LDS/VMEM overlap. Async DMA staging kept.

#define TDIM 1024
#define HH 8
#define SS 64
#define KK 31
#define CC 512
#define HK 248
#define TTILE 64
#define WIN 96
#define PAD 15
#define WSTRIDE 36     // 144 B row stride: 16B-aligned, 2-way-bank-alias only (free)

typedef float v4 __attribute__((ext_vector_type(4)));

__global__ __launch_bounds__(256, 4)
void lightconv_kernel(const float* __restrict__ xg,
                      const float* __restrict__ fg,
                      const float* __restrict__ bg,
                      float* __restrict__ og)
{
    __shared__ float xs[WIN * SS];          // 24576 B
    __shared__ float ws[TTILE * WSTRIDE];   // 9216 B   (total 33792 B -> 4 blocks/CU)

    const int t0  = blockIdx.x * TTILE;
    const int h   = blockIdx.y;
    const int b   = blockIdx.z;
    const int tid = threadIdx.x;

    const float* xb = xg + ((size_t)b * TDIM) * CC + h * SS;

    // ---- stage x window (96 rows x 64 ch) into LDS ----
    if (blockIdx.x != 0 && blockIdx.x != (TDIM / TTILE - 1)) {
        #pragma unroll
        for (int i = 0; i < 6; ++i) {
            int f  = tid + i * 256;        // quad 0..1535
            int r  = f >> 4;               // row 0..95
            int c4 = (f & 15) << 2;        // ch 0..60
            const float* gp = xb + (size_t)(t0 - PAD + r) * CC + c4;
            __builtin_amdgcn_global_load_lds(
                (const __attribute__((address_space(1))) void*)gp,
                (__attribute__((address_space(3))) void*)&xs[f << 2],
                16, 0, 0);
        }
    } else {
        #pragma unroll
        for (int i = 0; i < 6; ++i) {
            int f  = tid + i * 256;
            int r  = f >> 4;
            int c4 = (f & 15) << 2;
            int t  = t0 - PAD + r;
            v4 v = (v4)(0.f);
            if ((unsigned)t < (unsigned)TDIM)
                v = *reinterpret_cast<const v4*>(xb + (size_t)t * CC + c4);
            *reinterpret_cast<v4*>(&xs[f << 2]) = v;
        }
    }

    // ---- softmax over K: 4 threads per t-row, width-4 shuffle reduce ----
    {
        const int row  = tid >> 2;         // 0..63
        const int base = (tid & 3) * 8;    // taps base..base+7
        const float* fp = fg + (size_t)(b * TDIM + t0 + row) * HK + h * KK + base;
        float v[8];
        #pragma unroll
        for (int j = 0; j < 8; ++j)
            v[j] = (base + j < KK) ? fp[j] : -1e30f;
        float m = v[0];
        #pragma unroll
        for (int j = 1; j < 8; ++j) m = fmaxf(m, v[j]);
        m = fmaxf(m, __shfl_xor(m, 1, 4));
        m = fmaxf(m, __shfl_xor(m, 2, 4));
        float s = 0.f;
        #pragma unroll
        for (int j = 0; j < 8; ++j) { v[j] = __expf(v[j] - m); s += v[j]; }
        s += __shfl_xor(s, 1, 4);
        s += __shfl_xor(s, 2, 4);
        float inv = 1.f / s;
        #pragma unroll
        for (int j = 0; j < 8; ++j)
            if (base + j < 32)
                ws[row * WSTRIDE + base + j] = v[j] * inv;   // tap 31 -> exactly 0
    }
    __syncthreads();

    // ---- compute: 4 consecutive t-rows x 4 channels per thread ----
    const int sq = (tid & 15) << 2;       // ch offset 0..60
    const int tb = (tid >> 4) << 2;       // local t base 0..60

    const float* xbase = &xs[tb * SS + sq];
    const float* wbase = &ws[tb * WSTRIDE];

    // rolling 12-slot window of rows tb .. tb+34 (slot = row % 12)
    v4 xv[12];
    #pragma unroll
    for (int k = 0; k < 11; ++k)
        xv[k] = *reinterpret_cast<const v4*>(xbase + k * SS);

    v4 bias4 = *reinterpret_cast<const v4*>(bg + h * SS + sq);
    v4 acc[4];
    #pragma unroll
    for (int tt = 0; tt < 4; ++tt) acc[tt] = bias4;

    #pragma unroll
    for (int kq = 0; kq < 8; ++kq) {
        const int r = kq * 4;
        v4 w0 = *reinterpret_cast<const v4*>(wbase + 0 * WSTRIDE + r);
        v4 w1 = *reinterpret_cast<const v4*>(wbase + 1 * WSTRIDE + r);
        v4 w2 = *reinterpret_cast<const v4*>(wbase + 2 * WSTRIDE + r);
        v4 w3 = *reinterpret_cast<const v4*>(wbase + 3 * WSTRIDE + r);
        #pragma unroll
        for (int m = 0; m < 4; ++m) {
            acc[0] += xv[(r + 0 + m) % 12] * w0[m];   // -> v_pk_fma_f32 pairs
            acc[1] += xv[(r + 1 + m) % 12] * w1[m];
            acc[2] += xv[(r + 2 + m) % 12] * w2[m];
            acc[3] += xv[(r + 3 + m) % 12] * w3[m];
        }
        // refill: rows r+11 .. r+14 (dead slots), used 2 iterations later
        #pragma unroll
        for (int d = 0; d < 4; ++d) {
            int row = r + 11 + d;
            if (row < 35)
                xv[row % 12] = *reinterpret_cast<const v4*>(xbase + row * SS);
        }
    }

    // ---- store fp32 ----
    float* ob = og + (size_t)(b * TDIM + t0 + tb) * CC + h * SS + sq;
    #pragma unroll
    for (int tt = 0; tt < 4; ++tt)
        *reinterpret_cast<v4*>(ob + (size_t)tt * CC) = acc[tt];
}

extern "C" void kernel_launch(void* const* d_in, const int* in_sizes, int n_in,
                              void* d_out, int out_size, void* d_ws, size_t ws_size,
                              hipStream_t stream)
{
    const float* x    = (const float*)d_in[0];
    const float* f    = (const float*)d_in[1];
    const float* bias = (const float*)d_in[2];
    float* out        = (float*)d_out;
    dim3 grid(TDIM / TTILE, HH, 8);   // 16 x 8 x 8 = 1024 blocks
    lightconv_kernel<<<grid, 256, 0, stream>>>(x, f, bias, out);
}

// Round 7
// 80.903 us; speedup vs baseline: 1.1572x; 1.1572x over previous
//
#include <hip/hip_runtime.h>

// LightConv: B=8, T=1024, H=8, S=64, K=31, C=512 (all fp32)
// out[b,t,h*S+s] = sum_k softmax_k(filters[b,t,h,:])[k] * x[b, t+k-15, h*S+s] + bias[h*S+s]
//
// R7 = R4 (persistent 512 blocks x 2 tiles, double-buffered LDS, async DMA
// prefetch of tile i+1 across tile i's compute) + ONE change: compute uses
// float-v4 ext-vector math -> v_pk_fma_f32 (halves FMA issue cycles).
// launch_bounds(256,2): VGPR budget 256/wave, no spill risk (xw[35] = 140 VGPR).

#define TDIM 1024
#define HH 8
#define SS 64
#define KK 31
#define CC 512
#define HK 248
#define TTILE 64
#define WIN 96
#define PAD 15
#define WSTRIDE 36
#define NBLK 512

typedef float v4 __attribute__((ext_vector_type(4)));

__global__ __launch_bounds__(256, 2)
void lightconv_kernel(const float* __restrict__ xg,
                      const float* __restrict__ fg,
                      const float* __restrict__ bg,
                      float* __restrict__ og)
{
    __shared__ float xs[2][WIN * SS];          // 2 x 24576 B
    __shared__ float ws[2][TTILE * WSTRIDE];   // 2 x 9216 B

    const int tid = threadIdx.x;

    const int tx = blockIdx.x & 15;
    const int h  = (blockIdx.x >> 4) & 7;
    const int b0 = blockIdx.x >> 7;            // 0..3
    const int t0 = tx * TTILE;

    const int frow  = tid >> 2;                // softmax: 4 threads per t-row
    const int fbase = (tid & 3) * 8;

    const int sq = (tid & 15) << 2;            // compute: 4 t x 4 ch per thread
    const int tb = (tid >> 4) << 2;

    const bool interior = (tx != 0) && (tx != 15);

    auto load_filters = [&](int b, float* dst) {
        const float* fp = fg + (size_t)(b * TDIM + t0 + frow) * HK + h * KK + fbase;
        #pragma unroll
        for (int j = 0; j < 8; ++j)
            dst[j] = (fbase + j < KK) ? fp[j] : -1e30f;
    };

    auto stage = [&](int b, int buf) {
        const float* xb = xg + ((size_t)b * TDIM) * CC + h * SS;
        if (interior) {
            #pragma unroll
            for (int i = 0; i < 6; ++i) {
                int f  = tid + i * 256;        // quad 0..1535
                int r  = f >> 4;               // row 0..95
                int c4 = (f & 15) << 2;        // ch 0..60
                const float* gp = xb + (size_t)(t0 - PAD + r) * CC + c4;
                __builtin_amdgcn_global_load_lds(
                    (const __attribute__((address_space(1))) void*)gp,
                    (__attribute__((address_space(3))) void*)&xs[buf][f << 2],
                    16, 0, 0);
            }
        } else {
            #pragma unroll
            for (int i = 0; i < 6; ++i) {
                int f  = tid + i * 256;
                int r  = f >> 4;
                int c4 = (f & 15) << 2;
                int t  = t0 - PAD + r;
                v4 v = (v4)(0.f);
                if ((unsigned)t < (unsigned)TDIM)
                    v = *reinterpret_cast<const v4*>(xb + (size_t)t * CC + c4);
                *reinterpret_cast<v4*>(&xs[buf][f << 2]) = v;
            }
        }
    };

    auto softmax_to_lds = [&](int buf, float* v) {
        float m = v[0];
        #pragma unroll
        for (int j = 1; j < 8; ++j) m = fmaxf(m, v[j]);
        m = fmaxf(m, __shfl_xor(m, 1, 4));
        m = fmaxf(m, __shfl_xor(m, 2, 4));
        float s = 0.f;
        #pragma unroll
        for (int j = 0; j < 8; ++j) { v[j] = __expf(v[j] - m); s += v[j]; }
        s += __shfl_xor(s, 1, 4);
        s += __shfl_xor(s, 2, 4);
        float inv = 1.f / s;
        #pragma unroll
        for (int j = 0; j < 8; ++j)
            if (fbase + j < 32)
                ws[buf][frow * WSTRIDE + fbase + j] = v[j] * inv;  // tap 31 -> 0
    };

    v4 bias4 = *reinterpret_cast<const v4*>(bg + h * SS + sq);

    auto compute_store = [&](int b, int buf) {
        v4 xw[35];
        #pragma unroll
        for (int j = 0; j < 35; ++j)
            xw[j] = *reinterpret_cast<const v4*>(&xs[buf][(tb + j) * SS + sq]);

        v4 acc[4];
        #pragma unroll
        for (int tt = 0; tt < 4; ++tt) acc[tt] = bias4;

        #pragma unroll
        for (int tt = 0; tt < 4; ++tt) {
            #pragma unroll
            for (int kq = 0; kq < 8; ++kq) {
                v4 w4 = *reinterpret_cast<const v4*>(
                    &ws[buf][(tb + tt) * WSTRIDE + (kq << 2)]);
                #pragma unroll
                for (int m = 0; m < 4; ++m)
                    acc[tt] += xw[tt + (kq << 2) + m] * w4[m];   // v_pk_fma_f32 x2
            }
        }

        float* ob = og + (size_t)(b * TDIM + t0 + tb) * CC + h * SS + sq;
        #pragma unroll
        for (int tt = 0; tt < 4; ++tt)
            *reinterpret_cast<v4*>(ob + (size_t)tt * CC) = acc[tt];
    };

    const int b1 = b0 + 4;
    float fr0[8], fr1[8];

    load_filters(b0, fr0);
    stage(b0, 0);

    // ---- tile 0 ----
    softmax_to_lds(0, fr0);
    __syncthreads();               // drains tile-0 DMA + ws[0] writes
    stage(b1, 1);                  // tile-1 DMA flies across tile-0 compute
    load_filters(b1, fr1);
    compute_store(b0, 0);

    // ---- tile 1 ----
    softmax_to_lds(1, fr1);
    __syncthreads();               // drains tile-1 DMA + ws[1] writes
    compute_store(b1, 1);
}

extern "C" void kernel_launch(void* const* d_in, const int* in_sizes, int n_in,
                              void* d_out, int out_size, void* d_ws, size_t ws_size,
                              hipStream_t stream)
{
    const float* x    = (const float*)d_in[0];
    const float* f    = (const float*)d_in[1];
    const float* bias = (const float*)d_in[2];
    float* out        = (float*)d_out;
    lightconv_kernel<<<dim3(NBLK), 256, 0, stream>>>(x, f, bias, out);
}